// Round 10
// baseline (374.429 us; speedup 1.0000x reference)
//
#include <hip/hip_runtime.h>
#include <hip/hip_fp16.h>

#define N_NODES 50000
#define N_FEAT  128
#define HID     64
#define N_EDGES 800000
#define N_GRAPHS 64
#define MAXDEG  64
#define BN_EPS  1e-5f
#define NB256(n) (((n) + 255) / 256)

// ---------------- zero fill counters ----------------
__global__ __launch_bounds__(256) void k_zero(int* fill) {
    int i = blockIdx.x * 256 + threadIdx.x;
    if (i < N_NODES) fill[i] = 0;
}

// ---------------- fused dual-GEMM with piggybacked edge placement ----------------
#define GE_NB 2500
__global__ __launch_bounds__(256) void k_gemmedge(const int* __restrict__ ei,
                                                  int* fill, unsigned short* __restrict__ colp,
                                                  const float* __restrict__ x,
                                                  const float* __restrict__ W_in,
                                                  const float* __restrict__ W1,
                                                  float* __restrict__ h,
                                                  __half* __restrict__ g16) {
    __shared__ float4 Wt[2][8 * 65];   // 8 k4-slices of both W, stride 65 (conflict-free)
    __shared__ float4 xs[20 * 32];     // 20 node rows of x
    const int bid = blockIdx.x;
    const int t = threadIdx.x;

    // edge slice: issue atomics now, consume results after the GEMM
    const int ebase = bid * 320;
    int s1 = ei[ebase + t];
    int d1 = ei[N_EDGES + ebase + t];
    int k1 = atomicAdd(&fill[d1], 1);
    int s2 = 0, d2 = 0, k2 = MAXDEG;
    if (t < 64) {
        s2 = ei[ebase + 256 + t];
        d2 = ei[N_EDGES + ebase + 256 + t];
        k2 = atomicAdd(&fill[d2], 1);
    }

    // W chunk 0 prefetch into registers (each thread owns 2 slots of each W)
    const float4* W0v = (const float4*)W_in;
    const float4* W1v = (const float4*)W1;
    const int h2a = t >> 3, k4a = t & 7;
    const int h2b = h2a + 32;                 // second slot: i = t + 256
    float4 w0a = W0v[h2a * 32 + k4a];
    float4 w1a = W1v[h2a * 32 + k4a];
    float4 w0b = W0v[h2b * 32 + k4a];
    float4 w1b = W1v[h2b * 32 + k4a];

    const int base = bid * 20;
    const float4* xv = (const float4*)(x + (long long)base * N_FEAT);
    for (int i = t; i < 20 * 32; i += 256) xs[i] = xv[i];

    const int hh = t & 63;
    const int ng = t >> 6;
    float4 a0[5], a1[5];
#pragma unroll
    for (int j = 0; j < 5; ++j) {
        a0[j] = make_float4(0.f, 0.f, 0.f, 0.f);
        a1[j] = make_float4(0.f, 0.f, 0.f, 0.f);
    }

    for (int c = 0; c < 32; c += 8) {
        __syncthreads();  // WAR on Wt (also orders xs staging before first MAC)
        Wt[0][k4a * 65 + h2a] = w0a;  Wt[1][k4a * 65 + h2a] = w1a;
        Wt[0][k4a * 65 + h2b] = w0b;  Wt[1][k4a * 65 + h2b] = w1b;
        if (c + 8 < 32) {   // prefetch next chunk; latency hides under compute
            w0a = W0v[h2a * 32 + c + 8 + k4a]; w1a = W1v[h2a * 32 + c + 8 + k4a];
            w0b = W0v[h2b * 32 + c + 8 + k4a]; w1b = W1v[h2b * 32 + c + 8 + k4a];
        }
        __syncthreads();
#pragma unroll
        for (int k4 = 0; k4 < 8; ++k4) {
            float4 w0 = Wt[0][k4 * 65 + hh];
            float4 w1 = Wt[1][k4 * 65 + hh];
#pragma unroll
            for (int j = 0; j < 5; ++j) {
                float4 xx = xs[(ng + 4 * j) * 32 + c + k4];   // wave-broadcast
                a0[j].x += w0.x * xx.x; a0[j].y += w0.y * xx.y;
                a0[j].z += w0.z * xx.z; a0[j].w += w0.w * xx.w;
                a1[j].x += w1.x * xx.x; a1[j].y += w1.y * xx.y;
                a1[j].z += w1.z * xx.z; a1[j].w += w1.w * xx.w;
            }
        }
    }
#pragma unroll
    for (int j = 0; j < 5; ++j) {
        int node = base + ng + 4 * j;
        h[node * HID + hh]   = a0[j].x + a0[j].y + a0[j].z + a0[j].w;
        g16[node * HID + hh] = __float2half(a1[j].x + a1[j].y + a1[j].z + a1[j].w);
    }

    // deferred stores: atomic results long since returned
    if (k1 < MAXDEG) colp[d1 * MAXDEG + k1] = (unsigned short)s1;
    if (k2 < MAXDEG) colp[d2 * MAXDEG + k2] = (unsigned short)s2;
}

// ---- fp16 row accumulate, scaled (FMA — same cost as plain add) ----
__device__ __forceinline__ void acc8s(const uint4 r, float* a, float s) {
    float2 f0 = __half22float2(*(const __half2*)&r.x);
    float2 f1 = __half22float2(*(const __half2*)&r.y);
    float2 f2 = __half22float2(*(const __half2*)&r.z);
    float2 f3 = __half22float2(*(const __half2*)&r.w);
    a[0] += s * f0.x; a[1] += s * f0.y; a[2] += s * f1.x; a[3] += s * f1.y;
    a[4] += s * f2.x; a[5] += s * f2.y; a[6] += s * f3.x; a[7] += s * f3.y;
}

// ------ fused gather(+BN/ReLU/res) [+ per-wave GEMM], ONE node per WAVE ------
// R9->R10: node-per-wave. 64 lanes = 8 edge-slots (egrp) x 8 feature-octets
// (hh8). Per iteration the wave loads 8 edge rows (1 KB, one VMEM inst);
// trip = ceil(deg/8), WAVE-UNIFORM (deg is per-wave constant -> no sub
// imbalance, no __any). Cols preloaded once (128 B coalesced) + __shfl.
// Depth-2 pipeline with named regs. 50K waves (8x TLP of R9). Wt-staging
// barrier deferred to just before the GEMM epilogue.
template <bool NSCALE, bool DOGEMM>
__global__ __launch_bounds__(256) void k_gather_fused(const __half* __restrict__ gin,
                                                      const unsigned short* __restrict__ colp,
                                                      const int* __restrict__ fill,
                                                      const float* __restrict__ b,
                                                      const float* __restrict__ gamma,
                                                      const float* __restrict__ beta,
                                                      const float* __restrict__ mean,
                                                      const float* __restrict__ var,
                                                      const float4* __restrict__ res4,
                                                      float4* __restrict__ h4,
                                                      const float* __restrict__ W,
                                                      __half* __restrict__ gout) {
    __shared__ float4 Wt[DOGEMM ? 16 * 65 : 1];
    __shared__ float4 hrow[DOGEMM ? 4 * 17 : 1];   // one row per wave, stride 17

    const int t = threadIdx.x;
    const int wv = t >> 6;
    const int lane = t & 63;
    const int egrp = lane >> 3;     // edge slot 0..7
    const int hh8 = lane & 7;       // feature octet
    const int n = blockIdx.x * 4 + wv;   // 12500*4 = 50000 exact, always valid

    if (DOGEMM) {   // stage Wt; barrier deferred until the GEMM epilogue
        const float4* Wv = (const float4*)W;
        for (int i = t; i < HID * 16; i += 256) {
            int h2 = i >> 4, k4 = i & 15;
            Wt[k4 * 65 + h2] = Wv[i];
        }
    }

    const uint4* gv = (const uint4*)gin;  // row = 8 x uint4 (128 B)
    const int fl = fill[n];               // wave-uniform
    const int deg = fl < MAXDEG ? fl : MAXDEG;

    // one coalesced 128 B load: all 64 cols of this node (garbage past deg -> masked)
    int colall = (int)colp[(size_t)n * MAXDEG + lane];
    // self row: issue early, consumed after the reduce
    const uint4 vself = gv[(size_t)n * 8 + hh8];

    float a[8];
#pragma unroll
    for (int i = 0; i < 8; ++i) a[i] = 0.f;

    const int nit = (deg + 7) >> 3;       // wave-uniform trip count

#define FETCH_E(IT, C, S, V)                                              \
    {                                                                     \
        int j = ((IT) << 3) + egrp;                                       \
        int cc = __shfl(colall, j & 63);                                  \
        bool pv = j < deg;                                                \
        C = pv ? cc : 0;                                                  \
        if (NSCALE) S = pv ? rsqrtf((float)fill[C] + 1.0f) : 0.0f;        \
        else        S = pv ? 1.0f : 0.0f;                                 \
        V = gv[(size_t)C * 8 + hh8];                                      \
    }

    int cA; float sA; uint4 vA;
    FETCH_E(0, cA, sA, vA);
#pragma unroll 1
    for (int it = 0; it + 1 < nit; ++it) {
        int cB; float sB; uint4 vB;
        FETCH_E(it + 1, cB, sB, vB);      // next 8 rows in flight
        acc8s(vA, a, sA);                 // consume current
        cA = cB; sA = sB; vA = vB;
    }
    if (nit > 0) acc8s(vA, a, sA);
#undef FETCH_E

    // reduce across the 8 edge-slots (lane bits 3..5)
#pragma unroll
    for (int m = 8; m <= 32; m <<= 1) {
#pragma unroll
        for (int i = 0; i < 8; ++i) a[i] += __shfl_xor(a[i], m);
    }

    const float di = rsqrtf((float)fl + 1.0f);
    acc8s(vself, a, NSCALE ? di : 1.0f);  // self loop (post-reduce: added once per lane)

    // BN fold: o = a*di*SC + SH
    float o[8];
    {
        float4 b0 = ((const float4*)b)[hh8 * 2],     b1 = ((const float4*)b)[hh8 * 2 + 1];
        float4 g0 = ((const float4*)gamma)[hh8 * 2], g1 = ((const float4*)gamma)[hh8 * 2 + 1];
        float4 e0 = ((const float4*)beta)[hh8 * 2],  e1 = ((const float4*)beta)[hh8 * 2 + 1];
        float4 m0 = ((const float4*)mean)[hh8 * 2],  m1 = ((const float4*)mean)[hh8 * 2 + 1];
        float4 v0 = ((const float4*)var)[hh8 * 2],   v1 = ((const float4*)var)[hh8 * 2 + 1];
        float bb[8] = {b0.x, b0.y, b0.z, b0.w, b1.x, b1.y, b1.z, b1.w};
        float gg[8] = {g0.x, g0.y, g0.z, g0.w, g1.x, g1.y, g1.z, g1.w};
        float ee[8] = {e0.x, e0.y, e0.z, e0.w, e1.x, e1.y, e1.z, e1.w};
        float mm[8] = {m0.x, m0.y, m0.z, m0.w, m1.x, m1.y, m1.z, m1.w};
        float vv[8] = {v0.x, v0.y, v0.z, v0.w, v1.x, v1.y, v1.z, v1.w};
#pragma unroll
        for (int i = 0; i < 8; ++i) {
            float sc = gg[i] * rsqrtf(vv[i] + BN_EPS);
            float sh = (bb[i] - mm[i]) * sc + ee[i];
            o[i] = fmaxf(fmaf(a[i] * di, sc, sh), 0.f);
        }
    }

    if (res4 != nullptr) {
        float4 r0 = res4[(size_t)n * 16 + hh8 * 2];
        float4 r1 = res4[(size_t)n * 16 + hh8 * 2 + 1];
        o[0] += r0.x; o[1] += r0.y; o[2] += r0.z; o[3] += r0.w;
        o[4] += r1.x; o[5] += r1.y; o[6] += r1.z; o[7] += r1.w;
    }

    float4 lo = make_float4(o[0], o[1], o[2], o[3]);
    float4 hi = make_float4(o[4], o[5], o[6], o[7]);
    if (egrp == 0) {                       // lanes 0-7 cover the 16 float4 of the row
        h4[(size_t)n * 16 + hh8 * 2]     = lo;
        h4[(size_t)n * 16 + hh8 * 2 + 1] = hi;
    }

    if (DOGEMM) {
        if (egrp == 0) {                   // same-wave LDS write->read: in-order
            hrow[wv * 17 + hh8 * 2]     = lo;
            hrow[wv * 17 + hh8 * 2 + 1] = hi;
        }
        __syncthreads();                   // Wt staging visible (issued at kernel start)
        float acc = 0.f;
#pragma unroll 2
        for (int k4 = 0; k4 < 16; ++k4) {
            float4 w = Wt[k4 * 65 + lane];
            float4 hv = hrow[wv * 17 + k4];    // wave-broadcast (free)
            acc += hv.x * w.x + hv.y * w.y + hv.z * w.z + hv.w * w.w;
        }
        gout[(size_t)n * HID + lane] = __float2half(acc * di);
    }
}

// ---------------- pool + final linear: one 1024-thread block per graph ----------------
__device__ __forceinline__ int lowerb(const int* __restrict__ b, int val) {
    int lo = 0, hi = N_NODES;
    while (lo < hi) {
        int mid = (lo + hi) >> 1;
        if (b[mid] < val) lo = mid + 1; else hi = mid;
    }
    return lo;
}

__global__ __launch_bounds__(1024) void k_poolfinal(const float* __restrict__ h,
                                                    const int* __restrict__ batch,
                                                    const float* __restrict__ lin_w,
                                                    const float* __restrict__ lin_b,
                                                    float* __restrict__ out) {
    __shared__ float red[16][HID];
    int g = blockIdx.x;
    int w = threadIdx.x >> 6;
    int hh = threadIdx.x & 63;
    int start = lowerb(batch, g);
    int end = lowerb(batch, g + 1);
    int len = end - start;
    float acc = 0.f;
    for (int n = start + w; n < end; n += 16) acc += h[n * HID + hh];
    red[w][hh] = acc;
    __syncthreads();
    if (w == 0) {
        float s = 0.f;
#pragma unroll
        for (int i = 0; i < 16; ++i) s += red[i][hh];
        float c = fmaxf((float)len, 1.0f);
        float v = (s / c) * lin_w[hh];
#pragma unroll
        for (int off = 32; off > 0; off >>= 1) v += __shfl_down(v, off);
        if (hh == 0) out[g] = v + lin_b[0];
    }
}

extern "C" void kernel_launch(void* const* d_in, const int* in_sizes, int n_in,
                              void* d_out, int out_size, void* d_ws, size_t ws_size,
                              hipStream_t stream) {
    const float* x     = (const float*)d_in[0];
    const int*   ei    = (const int*)d_in[1];
    const int*   batch = (const int*)d_in[2];
    const float* W_in  = (const float*)d_in[3];
    const float* W1    = (const float*)d_in[4];
    const float* b1    = (const float*)d_in[5];
    const float* Ws    = (const float*)d_in[6];
    const float* bs_   = (const float*)d_in[7];
    const float* bn_g  = (const float*)d_in[8];
    const float* bn_b  = (const float*)d_in[9];
    const float* bn_m  = (const float*)d_in[10];
    const float* bn_v  = (const float*)d_in[11];
    const float* lin_w = (const float*)d_in[12];
    const float* lin_b = (const float*)d_in[13];
    float* out = (float*)d_out;

    char* q = (char*)d_ws;
    int*            fill = (int*)q;             q += (size_t)50048 * 4;
    unsigned short* colp = (unsigned short*)q;  q += (size_t)N_NODES * MAXDEG * 2;
    __half*         g16a = (__half*)q;          q += (size_t)N_NODES * HID * 2;
    __half*         g16b = (__half*)q;          q += (size_t)N_NODES * HID * 2;
    float*          h    = (float*)q;           q += (size_t)N_NODES * HID * 4;

    const int NB_N  = NB256(N_NODES);
    const int NB_GA = N_NODES / 4;   // 12500 blocks, 1 node/wave
    float4* h4 = (float4*)h;

    // zero fill, then fused dual-GEMM (identity + layer-1) with deferred-store edge placement
    k_zero<<<NB_N, 256, 0, stream>>>(fill);
    k_gemmedge<<<GE_NB, 256, 0, stream>>>(ei, fill, colp, x, W_in, W1, h, g16a);

    // layer 1: gather (per-source dinv; g16a unscaled) + fused gemm for layer 2
    k_gather_fused<true, true><<<NB_GA, 256, 0, stream>>>(
        g16a, colp, fill, b1, bn_g, bn_b, bn_m, bn_v,
        (const float4*)h, h4, Ws + 0 * HID * HID, g16b);

    // layers 2-4: gather (pre-scaled g16) + fused gemm for next layer
    k_gather_fused<false, true><<<NB_GA, 256, 0, stream>>>(
        g16b, colp, fill, bs_ + 0 * HID,
        bn_g + 1 * HID, bn_b + 1 * HID, bn_m + 1 * HID, bn_v + 1 * HID,
        (const float4*)h, h4, Ws + 1 * HID * HID, g16a);

    k_gather_fused<false, true><<<NB_GA, 256, 0, stream>>>(
        g16a, colp, fill, bs_ + 1 * HID,
        bn_g + 2 * HID, bn_b + 2 * HID, bn_m + 2 * HID, bn_v + 2 * HID,
        (const float4*)h, h4, Ws + 2 * HID * HID, g16b);

    k_gather_fused<false, true><<<NB_GA, 256, 0, stream>>>(
        g16b, colp, fill, bs_ + 2 * HID,
        bn_g + 3 * HID, bn_b + 3 * HID, bn_m + 3 * HID, bn_v + 3 * HID,
        (const float4*)h, h4, Ws + 3 * HID * HID, g16a);

    // layer 5: gather only (no residual, no next gemm)
    k_gather_fused<false, false><<<NB_GA, 256, 0, stream>>>(
        g16a, colp, fill, bs_ + 3 * HID,
        bn_g + 4 * HID, bn_b + 4 * HID, bn_m + 4 * HID, bn_v + 4 * HID,
        nullptr, h4, nullptr, nullptr);

    // pool + final
    k_poolfinal<<<N_GRAPHS, 1024, 0, stream>>>(h, batch, lin_w, lin_b, out);
}

// Round 11
// 319.523 us; speedup vs baseline: 1.1718x; 1.1718x over previous
//
#include <hip/hip_runtime.h>
#include <hip/hip_fp16.h>

#define N_NODES 50000
#define N_FEAT  128
#define HID     64
#define N_EDGES 800000
#define N_GRAPHS 64
#define MAXDEG  64
#define BN_EPS  1e-5f
#define NB256(n) (((n) + 255) / 256)

// ---------------- zero fill counters ----------------
__global__ __launch_bounds__(256) void k_zero(int* fill) {
    int i = blockIdx.x * 256 + threadIdx.x;
    if (i < N_NODES) fill[i] = 0;
}

// ---------------- fused dual-GEMM with piggybacked edge placement ----------------
// R10->R11: ONE barrier total. Both W staged fully to LDS (66.6 KB, stride-65
// pad — staging writes are 32-way bank-conflicted without it), xs 10.2 KB.
// The 32-step K loop is barrier-free (was 4 chunks x 2 barriers = 8 drains,
// ~half the kernel's 57-70 us at VALUBusy 19%). 76.8 KB -> 2 blocks/CU, which
// equals the measured 8 waves/CU occupancy anyway.
#define GE_NB 2500
__global__ __launch_bounds__(256) void k_gemmedge(const int* __restrict__ ei,
                                                  int* fill, unsigned short* __restrict__ colp,
                                                  const float* __restrict__ x,
                                                  const float* __restrict__ W_in,
                                                  const float* __restrict__ W1,
                                                  float* __restrict__ h,
                                                  __half* __restrict__ g16) {
    __shared__ float4 Wt[2][32 * 65];  // full W_in + W1, stride 65
    __shared__ float4 xs[20 * 32];     // 20 node rows of x
    const int bid = blockIdx.x;
    const int t = threadIdx.x;

    // edge slice: issue atomics now, consume results after the GEMM
    const int ebase = bid * 320;
    int s1 = ei[ebase + t];
    int d1 = ei[N_EDGES + ebase + t];
    int k1 = atomicAdd(&fill[d1], 1);
    int s2 = 0, d2 = 0, k2 = MAXDEG;
    if (t < 64) {
        s2 = ei[ebase + 256 + t];
        d2 = ei[N_EDGES + ebase + 256 + t];
        k2 = atomicAdd(&fill[d2], 1);
    }

    // stage BOTH W fully (64 rows x 32 float4 each)
    const float4* W0v = (const float4*)W_in;
    const float4* W1v = (const float4*)W1;
    for (int i = t; i < 64 * 32; i += 256) {
        int h2 = i >> 5, k4 = i & 31;
        Wt[0][k4 * 65 + h2] = W0v[i];
        Wt[1][k4 * 65 + h2] = W1v[i];
    }

    const int base = bid * 20;
    const float4* xv = (const float4*)(x + (long long)base * N_FEAT);
    for (int i = t; i < 20 * 32; i += 256) xs[i] = xv[i];

    __syncthreads();   // the ONLY barrier: W + xs staged

    const int hh = t & 63;
    const int ng = t >> 6;
    float4 a0[5], a1[5];
#pragma unroll
    for (int j = 0; j < 5; ++j) {
        a0[j] = make_float4(0.f, 0.f, 0.f, 0.f);
        a1[j] = make_float4(0.f, 0.f, 0.f, 0.f);
    }

#pragma unroll 4
    for (int c = 0; c < 32; ++c) {
        float4 w0 = Wt[0][c * 65 + hh];
        float4 w1 = Wt[1][c * 65 + hh];
#pragma unroll
        for (int j = 0; j < 5; ++j) {
            float4 xx = xs[(ng + 4 * j) * 32 + c];   // wave-broadcast
            a0[j].x += w0.x * xx.x; a0[j].y += w0.y * xx.y;
            a0[j].z += w0.z * xx.z; a0[j].w += w0.w * xx.w;
            a1[j].x += w1.x * xx.x; a1[j].y += w1.y * xx.y;
            a1[j].z += w1.z * xx.z; a1[j].w += w1.w * xx.w;
        }
    }
#pragma unroll
    for (int j = 0; j < 5; ++j) {
        int node = base + ng + 4 * j;
        h[node * HID + hh]   = a0[j].x + a0[j].y + a0[j].z + a0[j].w;
        g16[node * HID + hh] = __float2half(a1[j].x + a1[j].y + a1[j].z + a1[j].w);
    }

    // deferred stores: atomic results long since returned
    if (k1 < MAXDEG) colp[d1 * MAXDEG + k1] = (unsigned short)s1;
    if (k2 < MAXDEG) colp[d2 * MAXDEG + k2] = (unsigned short)s2;
}

// ---- fp16 row accumulate, scaled (FMA — same cost as plain add) ----
__device__ __forceinline__ void acc8s(const uint4 r, float* a, float s) {
    float2 f0 = __half22float2(*(const __half2*)&r.x);
    float2 f1 = __half22float2(*(const __half2*)&r.y);
    float2 f2 = __half22float2(*(const __half2*)&r.z);
    float2 f3 = __half22float2(*(const __half2*)&r.w);
    a[0] += s * f0.x; a[1] += s * f0.y; a[2] += s * f1.x; a[3] += s * f1.y;
    a[4] += s * f2.x; a[5] += s * f2.y; a[6] += s * f3.x; a[7] += s * f3.y;
}

// ------ fused gather(+BN/ReLU/res) [+ per-wave GEMM], ONE node per 8-lane sub ------
// Reverted to R9 (best measured: 311 us total). 1563 blocks x 32 nodes,
// 8-wide gather body, unroll 1, post-loop BN/residual, launch_bounds(256,4).
template <bool NSCALE, bool DOGEMM>
__global__ __launch_bounds__(256, 4) void k_gather_fused(const __half* __restrict__ gin,
                                                      const unsigned short* __restrict__ colp,
                                                      const int* __restrict__ fill,
                                                      const float* __restrict__ b,
                                                      const float* __restrict__ gamma,
                                                      const float* __restrict__ beta,
                                                      const float* __restrict__ mean,
                                                      const float* __restrict__ var,
                                                      const float4* __restrict__ res4,
                                                      float4* __restrict__ h4,
                                                      const float* __restrict__ W,
                                                      __half* __restrict__ gout) {
    __shared__ float4 Wt[DOGEMM ? 16 * 65 : 1];
    __shared__ float4 hrow[DOGEMM ? 32 * 17 : 1];   // stride 17

    const int t = threadIdx.x;
    const int wv = t >> 6;
    const int lane = t & 63;
    const int hh8 = lane & 7;       // feature octet
    const int sub = lane >> 3;      // node slot within wave
    const int nl = wv * 8 + sub;    // local node 0..31
    const int n = blockIdx.x * 32 + nl;
    const bool nvalid = (n < N_NODES);

    if (DOGEMM) {
        const float4* Wv = (const float4*)W;
        for (int i = t; i < HID * 16; i += 256) {
            int h2 = i >> 4, k4 = i & 15;
            Wt[k4 * 65 + h2] = Wv[i];
        }
        __syncthreads();   // only block barrier: Wt visible before any use
    }

    const uint4* gv = (const uint4*)gin;  // row = 8 x uint4 (128 B)
    const int fl = nvalid ? fill[n] : 0;
    const int deg = fl < MAXDEG ? fl : MAXDEG;

    float a[8];
#pragma unroll
    for (int i = 0; i < 8; ++i) a[i] = 0.f;

    const uint4* cp8 = (const uint4*)(colp + (size_t)n * MAXDEG);  // 8 cols / 16 B

#pragma unroll 1
    for (int rb = 0; rb < MAXDEG; rb += 8) {
        if (!__any(rb < deg)) break;          // wave-uniform exit
        if (rb < deg) {                       // sub-uniform mask (8 lanes alike)
            uint4 cc = cp8[rb >> 3];          // 8 packed cols, one 16B load
            unsigned cw[4] = {cc.x, cc.y, cc.z, cc.w};
            int c[8]; float s[8]; uint4 v[8];
#pragma unroll
            for (int k = 0; k < 8; ++k) {
                bool pk = (rb + k) < deg;
                int col = (int)((cw[k >> 1] >> (16 * (k & 1))) & 0xFFFFu);
                c[k] = pk ? col : 0;
                if (NSCALE) s[k] = pk ? rsqrtf((float)fill[c[k]] + 1.0f) : 0.0f;
                else        s[k] = pk ? 1.0f : 0.0f;
            }
#pragma unroll
            for (int k = 0; k < 8; ++k) v[k] = gv[(size_t)c[k] * 8 + hh8];
#pragma unroll
            for (int k = 0; k < 8; ++k) acc8s(v[k], a, s[k]);
        }
    }

    const float di = rsqrtf((float)fl + 1.0f);
    if (nvalid) acc8s(gv[(size_t)n * 8 + hh8], a, NSCALE ? di : 1.0f);  // self loop

    // BN fold (post-loop; params from L2): o = a*di*SC + SH
    float o[8];
    {
        float4 b0 = ((const float4*)b)[hh8 * 2],     b1 = ((const float4*)b)[hh8 * 2 + 1];
        float4 g0 = ((const float4*)gamma)[hh8 * 2], g1 = ((const float4*)gamma)[hh8 * 2 + 1];
        float4 e0 = ((const float4*)beta)[hh8 * 2],  e1 = ((const float4*)beta)[hh8 * 2 + 1];
        float4 m0 = ((const float4*)mean)[hh8 * 2],  m1 = ((const float4*)mean)[hh8 * 2 + 1];
        float4 v0 = ((const float4*)var)[hh8 * 2],   v1 = ((const float4*)var)[hh8 * 2 + 1];
        float bb[8] = {b0.x, b0.y, b0.z, b0.w, b1.x, b1.y, b1.z, b1.w};
        float gg[8] = {g0.x, g0.y, g0.z, g0.w, g1.x, g1.y, g1.z, g1.w};
        float ee[8] = {e0.x, e0.y, e0.z, e0.w, e1.x, e1.y, e1.z, e1.w};
        float mm[8] = {m0.x, m0.y, m0.z, m0.w, m1.x, m1.y, m1.z, m1.w};
        float vv[8] = {v0.x, v0.y, v0.z, v0.w, v1.x, v1.y, v1.z, v1.w};
#pragma unroll
        for (int i = 0; i < 8; ++i) {
            float sc = gg[i] * rsqrtf(vv[i] + BN_EPS);
            float sh = (bb[i] - mm[i]) * sc + ee[i];
            o[i] = fmaxf(fmaf(a[i] * di, sc, sh), 0.f);
        }
    }

    // residual (loaded post-loop: L2-resident, consumed immediately)
    if (res4 != nullptr && nvalid) {
        float4 r0 = res4[(size_t)n * 16 + hh8 * 2];
        float4 r1 = res4[(size_t)n * 16 + hh8 * 2 + 1];
        o[0] += r0.x; o[1] += r0.y; o[2] += r0.z; o[3] += r0.w;
        o[4] += r1.x; o[5] += r1.y; o[6] += r1.z; o[7] += r1.w;
    }

    float4 lo = make_float4(o[0], o[1], o[2], o[3]);
    float4 hi = make_float4(o[4], o[5], o[6], o[7]);
    if (nvalid) {
        h4[(size_t)n * 16 + hh8 * 2]     = lo;
        h4[(size_t)n * 16 + hh8 * 2 + 1] = hi;
    }

    if (DOGEMM) {
        // same-wave LDS write->read (rows wv*8..wv*8+7 only): in-order, no barrier
        hrow[nl * 17 + hh8 * 2]     = lo;
        hrow[nl * 17 + hh8 * 2 + 1] = hi;
        const int hh = lane;
        const int nb = blockIdx.x * 32 + wv * 8;
        float acc[8];
#pragma unroll
        for (int s8 = 0; s8 < 8; ++s8) acc[s8] = 0.f;
#pragma unroll 2
        for (int k4 = 0; k4 < 16; ++k4) {
            float4 w = Wt[k4 * 65 + hh];
#pragma unroll
            for (int s8 = 0; s8 < 8; ++s8) {
                float4 hv = hrow[(wv * 8 + s8) * 17 + k4];   // wave-broadcast (free)
                acc[s8] += hv.x * w.x + hv.y * w.y + hv.z * w.z + hv.w * w.w;
            }
        }
#pragma unroll
        for (int s8 = 0; s8 < 8; ++s8) {
            int ns = nb + s8;
            if (ns < N_NODES) {
                float dd = rsqrtf((float)fill[ns] + 1.0f);
                gout[(size_t)ns * HID + hh] = __float2half(acc[s8] * dd);
            }
        }
    }
}

// ---------------- pool + final linear: one 1024-thread block per graph ----------------
__device__ __forceinline__ int lowerb(const int* __restrict__ b, int val) {
    int lo = 0, hi = N_NODES;
    while (lo < hi) {
        int mid = (lo + hi) >> 1;
        if (b[mid] < val) lo = mid + 1; else hi = mid;
    }
    return lo;
}

__global__ __launch_bounds__(1024) void k_poolfinal(const float* __restrict__ h,
                                                    const int* __restrict__ batch,
                                                    const float* __restrict__ lin_w,
                                                    const float* __restrict__ lin_b,
                                                    float* __restrict__ out) {
    __shared__ float red[16][HID];
    int g = blockIdx.x;
    int w = threadIdx.x >> 6;
    int hh = threadIdx.x & 63;
    int start = lowerb(batch, g);
    int end = lowerb(batch, g + 1);
    int len = end - start;
    float acc = 0.f;
    for (int n = start + w; n < end; n += 16) acc += h[n * HID + hh];
    red[w][hh] = acc;
    __syncthreads();
    if (w == 0) {
        float s = 0.f;
#pragma unroll
        for (int i = 0; i < 16; ++i) s += red[i][hh];
        float c = fmaxf((float)len, 1.0f);
        float v = (s / c) * lin_w[hh];
#pragma unroll
        for (int off = 32; off > 0; off >>= 1) v += __shfl_down(v, off);
        if (hh == 0) out[g] = v + lin_b[0];
    }
}

extern "C" void kernel_launch(void* const* d_in, const int* in_sizes, int n_in,
                              void* d_out, int out_size, void* d_ws, size_t ws_size,
                              hipStream_t stream) {
    const float* x     = (const float*)d_in[0];
    const int*   ei    = (const int*)d_in[1];
    const int*   batch = (const int*)d_in[2];
    const float* W_in  = (const float*)d_in[3];
    const float* W1    = (const float*)d_in[4];
    const float* b1    = (const float*)d_in[5];
    const float* Ws    = (const float*)d_in[6];
    const float* bs_   = (const float*)d_in[7];
    const float* bn_g  = (const float*)d_in[8];
    const float* bn_b  = (const float*)d_in[9];
    const float* bn_m  = (const float*)d_in[10];
    const float* bn_v  = (const float*)d_in[11];
    const float* lin_w = (const float*)d_in[12];
    const float* lin_b = (const float*)d_in[13];
    float* out = (float*)d_out;

    char* q = (char*)d_ws;
    int*            fill = (int*)q;             q += (size_t)50048 * 4;
    unsigned short* colp = (unsigned short*)q;  q += (size_t)N_NODES * MAXDEG * 2;
    __half*         g16a = (__half*)q;          q += (size_t)N_NODES * HID * 2;
    __half*         g16b = (__half*)q;          q += (size_t)N_NODES * HID * 2;
    float*          h    = (float*)q;           q += (size_t)N_NODES * HID * 4;

    const int NB_N  = NB256(N_NODES);
    const int NB_GA = (N_NODES + 31) / 32;   // 1563
    float4* h4 = (float4*)h;

    // zero fill, then fused dual-GEMM (identity + layer-1) with deferred-store edge placement
    k_zero<<<NB_N, 256, 0, stream>>>(fill);
    k_gemmedge<<<GE_NB, 256, 0, stream>>>(ei, fill, colp, x, W_in, W1, h, g16a);

    // layer 1: gather (per-source dinv; g16a unscaled) + fused gemm for layer 2
    k_gather_fused<true, true><<<NB_GA, 256, 0, stream>>>(
        g16a, colp, fill, b1, bn_g, bn_b, bn_m, bn_v,
        (const float4*)h, h4, Ws + 0 * HID * HID, g16b);

    // layers 2-4: gather (pre-scaled g16) + fused gemm for next layer
    k_gather_fused<false, true><<<NB_GA, 256, 0, stream>>>(
        g16b, colp, fill, bs_ + 0 * HID,
        bn_g + 1 * HID, bn_b + 1 * HID, bn_m + 1 * HID, bn_v + 1 * HID,
        (const float4*)h, h4, Ws + 1 * HID * HID, g16a);

    k_gather_fused<false, true><<<NB_GA, 256, 0, stream>>>(
        g16a, colp, fill, bs_ + 1 * HID,
        bn_g + 2 * HID, bn_b + 2 * HID, bn_m + 2 * HID, bn_v + 2 * HID,
        (const float4*)h, h4, Ws + 2 * HID * HID, g16b);

    k_gather_fused<false, true><<<NB_GA, 256, 0, stream>>>(
        g16b, colp, fill, bs_ + 2 * HID,
        bn_g + 3 * HID, bn_b + 3 * HID, bn_m + 3 * HID, bn_v + 3 * HID,
        (const float4*)h, h4, Ws + 3 * HID * HID, g16a);

    // layer 5: gather only (no residual, no next gemm)
    k_gather_fused<false, false><<<NB_GA, 256, 0, stream>>>(
        g16a, colp, fill, bs_ + 3 * HID,
        bn_g + 4 * HID, bn_b + 4 * HID, bn_m + 4 * HID, bn_v + 4 * HID,
        nullptr, h4, nullptr, nullptr);

    // pool + final
    k_poolfinal<<<N_GRAPHS, 1024, 0, stream>>>(h, batch, lin_w, lin_b, out);
}

// Round 12
// 310.505 us; speedup vs baseline: 1.2059x; 1.0290x over previous
//
#include <hip/hip_runtime.h>
#include <hip/hip_fp16.h>

#define N_NODES 50000
#define N_FEAT  128
#define HID     64
#define N_EDGES 800000
#define N_GRAPHS 64
#define MAXDEG  64
#define BN_EPS  1e-5f
#define NB256(n) (((n) + 255) / 256)

// ---------------- zero fill counters ----------------
__global__ __launch_bounds__(256) void k_zero(int* fill) {
    int i = blockIdx.x * 256 + threadIdx.x;
    if (i < N_NODES) fill[i] = 0;
}

// ---------------- fused dual-GEMM with piggybacked edge placement ----------------
// Chunked W staging (8 k4-slices, 2 barriers/chunk) + register prefetch of the
// next chunk. R11's one-barrier/full-W variant REGRESSED (76.8 KB LDS -> 18%
// occupancy): the barriers were cheap, occupancy wasn't. This is the measured
// best (~57-70 us run-to-run).
#define GE_NB 2500
__global__ __launch_bounds__(256) void k_gemmedge(const int* __restrict__ ei,
                                                  int* fill, unsigned short* __restrict__ colp,
                                                  const float* __restrict__ x,
                                                  const float* __restrict__ W_in,
                                                  const float* __restrict__ W1,
                                                  float* __restrict__ h,
                                                  __half* __restrict__ g16) {
    __shared__ float4 Wt[2][8 * 65];   // 8 k4-slices of both W, stride 65 (conflict-free)
    __shared__ float4 xs[20 * 32];     // 20 node rows of x
    const int bid = blockIdx.x;
    const int t = threadIdx.x;

    // edge slice: issue atomics now, consume results after the GEMM
    const int ebase = bid * 320;
    int s1 = ei[ebase + t];
    int d1 = ei[N_EDGES + ebase + t];
    int k1 = atomicAdd(&fill[d1], 1);
    int s2 = 0, d2 = 0, k2 = MAXDEG;
    if (t < 64) {
        s2 = ei[ebase + 256 + t];
        d2 = ei[N_EDGES + ebase + 256 + t];
        k2 = atomicAdd(&fill[d2], 1);
    }

    // W chunk 0 prefetch into registers (each thread owns 2 slots of each W)
    const float4* W0v = (const float4*)W_in;
    const float4* W1v = (const float4*)W1;
    const int h2a = t >> 3, k4a = t & 7;
    const int h2b = h2a + 32;                 // second slot: i = t + 256
    float4 w0a = W0v[h2a * 32 + k4a];
    float4 w1a = W1v[h2a * 32 + k4a];
    float4 w0b = W0v[h2b * 32 + k4a];
    float4 w1b = W1v[h2b * 32 + k4a];

    const int base = bid * 20;
    const float4* xv = (const float4*)(x + (long long)base * N_FEAT);
    for (int i = t; i < 20 * 32; i += 256) xs[i] = xv[i];

    const int hh = t & 63;
    const int ng = t >> 6;
    float4 a0[5], a1[5];
#pragma unroll
    for (int j = 0; j < 5; ++j) {
        a0[j] = make_float4(0.f, 0.f, 0.f, 0.f);
        a1[j] = make_float4(0.f, 0.f, 0.f, 0.f);
    }

    for (int c = 0; c < 32; c += 8) {
        __syncthreads();  // WAR on Wt (also orders xs staging before first MAC)
        Wt[0][k4a * 65 + h2a] = w0a;  Wt[1][k4a * 65 + h2a] = w1a;
        Wt[0][k4a * 65 + h2b] = w0b;  Wt[1][k4a * 65 + h2b] = w1b;
        if (c + 8 < 32) {   // prefetch next chunk; latency hides under compute
            w0a = W0v[h2a * 32 + c + 8 + k4a]; w1a = W1v[h2a * 32 + c + 8 + k4a];
            w0b = W0v[h2b * 32 + c + 8 + k4a]; w1b = W1v[h2b * 32 + c + 8 + k4a];
        }
        __syncthreads();
#pragma unroll
        for (int k4 = 0; k4 < 8; ++k4) {
            float4 w0 = Wt[0][k4 * 65 + hh];
            float4 w1 = Wt[1][k4 * 65 + hh];
#pragma unroll
            for (int j = 0; j < 5; ++j) {
                float4 xx = xs[(ng + 4 * j) * 32 + c + k4];   // wave-broadcast
                a0[j].x += w0.x * xx.x; a0[j].y += w0.y * xx.y;
                a0[j].z += w0.z * xx.z; a0[j].w += w0.w * xx.w;
                a1[j].x += w1.x * xx.x; a1[j].y += w1.y * xx.y;
                a1[j].z += w1.z * xx.z; a1[j].w += w1.w * xx.w;
            }
        }
    }
#pragma unroll
    for (int j = 0; j < 5; ++j) {
        int node = base + ng + 4 * j;
        h[node * HID + hh]   = a0[j].x + a0[j].y + a0[j].z + a0[j].w;
        g16[node * HID + hh] = __float2half(a1[j].x + a1[j].y + a1[j].z + a1[j].w);
    }

    // deferred stores: atomic results long since returned
    if (k1 < MAXDEG) colp[d1 * MAXDEG + k1] = (unsigned short)s1;
    if (k2 < MAXDEG) colp[d2 * MAXDEG + k2] = (unsigned short)s2;
}

// ---- fp16 row accumulate, scaled (FMA — same cost as plain add) ----
__device__ __forceinline__ void acc8s(const uint4 r, float* a, float s) {
    float2 f0 = __half22float2(*(const __half2*)&r.x);
    float2 f1 = __half22float2(*(const __half2*)&r.y);
    float2 f2 = __half22float2(*(const __half2*)&r.z);
    float2 f3 = __half22float2(*(const __half2*)&r.w);
    a[0] += s * f0.x; a[1] += s * f0.y; a[2] += s * f1.x; a[3] += s * f1.y;
    a[4] += s * f2.x; a[5] += s * f2.y; a[6] += s * f3.x; a[7] += s * f3.y;
}

// ------ fused gather(+BN/ReLU/res) [+ per-wave GEMM], ONE node per 8-lane sub ------
// Measured-best gather (R9, 311 us total). 1563 blocks x 32 nodes, 8-wide
// body under unroll 1, post-loop BN/residual, launch_bounds(256,4).
// Seven structural variants (2-node/wave, 8-wide, hoisted, depth-2 pipeline,
// occupancy-forced, node-per-wave) all measured 47-54 us/layer -> consistent
// with a chip-level random-128B-request-rate ceiling (~16 G req/s), not
// latency/ILP/occupancy.
template <bool NSCALE, bool DOGEMM>
__global__ __launch_bounds__(256, 4) void k_gather_fused(const __half* __restrict__ gin,
                                                      const unsigned short* __restrict__ colp,
                                                      const int* __restrict__ fill,
                                                      const float* __restrict__ b,
                                                      const float* __restrict__ gamma,
                                                      const float* __restrict__ beta,
                                                      const float* __restrict__ mean,
                                                      const float* __restrict__ var,
                                                      const float4* __restrict__ res4,
                                                      float4* __restrict__ h4,
                                                      const float* __restrict__ W,
                                                      __half* __restrict__ gout) {
    __shared__ float4 Wt[DOGEMM ? 16 * 65 : 1];
    __shared__ float4 hrow[DOGEMM ? 32 * 17 : 1];   // stride 17

    const int t = threadIdx.x;
    const int wv = t >> 6;
    const int lane = t & 63;
    const int hh8 = lane & 7;       // feature octet
    const int sub = lane >> 3;      // node slot within wave
    const int nl = wv * 8 + sub;    // local node 0..31
    const int n = blockIdx.x * 32 + nl;
    const bool nvalid = (n < N_NODES);

    if (DOGEMM) {
        const float4* Wv = (const float4*)W;
        for (int i = t; i < HID * 16; i += 256) {
            int h2 = i >> 4, k4 = i & 15;
            Wt[k4 * 65 + h2] = Wv[i];
        }
        __syncthreads();   // only block barrier: Wt visible before any use
    }

    const uint4* gv = (const uint4*)gin;  // row = 8 x uint4 (128 B)
    const int fl = nvalid ? fill[n] : 0;
    const int deg = fl < MAXDEG ? fl : MAXDEG;

    float a[8];
#pragma unroll
    for (int i = 0; i < 8; ++i) a[i] = 0.f;

    const uint4* cp8 = (const uint4*)(colp + (size_t)n * MAXDEG);  // 8 cols / 16 B

#pragma unroll 1
    for (int rb = 0; rb < MAXDEG; rb += 8) {
        if (!__any(rb < deg)) break;          // wave-uniform exit
        if (rb < deg) {                       // sub-uniform mask (8 lanes alike)
            uint4 cc = cp8[rb >> 3];          // 8 packed cols, one 16B load
            unsigned cw[4] = {cc.x, cc.y, cc.z, cc.w};
            int c[8]; float s[8]; uint4 v[8];
#pragma unroll
            for (int k = 0; k < 8; ++k) {
                bool pk = (rb + k) < deg;
                int col = (int)((cw[k >> 1] >> (16 * (k & 1))) & 0xFFFFu);
                c[k] = pk ? col : 0;
                if (NSCALE) s[k] = pk ? rsqrtf((float)fill[c[k]] + 1.0f) : 0.0f;
                else        s[k] = pk ? 1.0f : 0.0f;
            }
#pragma unroll
            for (int k = 0; k < 8; ++k) v[k] = gv[(size_t)c[k] * 8 + hh8];
#pragma unroll
            for (int k = 0; k < 8; ++k) acc8s(v[k], a, s[k]);
        }
    }

    const float di = rsqrtf((float)fl + 1.0f);
    if (nvalid) acc8s(gv[(size_t)n * 8 + hh8], a, NSCALE ? di : 1.0f);  // self loop

    // BN fold (post-loop; params from L2): o = a*di*SC + SH
    float o[8];
    {
        float4 b0 = ((const float4*)b)[hh8 * 2],     b1 = ((const float4*)b)[hh8 * 2 + 1];
        float4 g0 = ((const float4*)gamma)[hh8 * 2], g1 = ((const float4*)gamma)[hh8 * 2 + 1];
        float4 e0 = ((const float4*)beta)[hh8 * 2],  e1 = ((const float4*)beta)[hh8 * 2 + 1];
        float4 m0 = ((const float4*)mean)[hh8 * 2],  m1 = ((const float4*)mean)[hh8 * 2 + 1];
        float4 v0 = ((const float4*)var)[hh8 * 2],   v1 = ((const float4*)var)[hh8 * 2 + 1];
        float bb[8] = {b0.x, b0.y, b0.z, b0.w, b1.x, b1.y, b1.z, b1.w};
        float gg[8] = {g0.x, g0.y, g0.z, g0.w, g1.x, g1.y, g1.z, g1.w};
        float ee[8] = {e0.x, e0.y, e0.z, e0.w, e1.x, e1.y, e1.z, e1.w};
        float mm[8] = {m0.x, m0.y, m0.z, m0.w, m1.x, m1.y, m1.z, m1.w};
        float vv[8] = {v0.x, v0.y, v0.z, v0.w, v1.x, v1.y, v1.z, v1.w};
#pragma unroll
        for (int i = 0; i < 8; ++i) {
            float sc = gg[i] * rsqrtf(vv[i] + BN_EPS);
            float sh = (bb[i] - mm[i]) * sc + ee[i];
            o[i] = fmaxf(fmaf(a[i] * di, sc, sh), 0.f);
        }
    }

    // residual (loaded post-loop: L2-resident, consumed immediately)
    if (res4 != nullptr && nvalid) {
        float4 r0 = res4[(size_t)n * 16 + hh8 * 2];
        float4 r1 = res4[(size_t)n * 16 + hh8 * 2 + 1];
        o[0] += r0.x; o[1] += r0.y; o[2] += r0.z; o[3] += r0.w;
        o[4] += r1.x; o[5] += r1.y; o[6] += r1.z; o[7] += r1.w;
    }

    float4 lo = make_float4(o[0], o[1], o[2], o[3]);
    float4 hi = make_float4(o[4], o[5], o[6], o[7]);
    if (nvalid) {
        h4[(size_t)n * 16 + hh8 * 2]     = lo;
        h4[(size_t)n * 16 + hh8 * 2 + 1] = hi;
    }

    if (DOGEMM) {
        // same-wave LDS write->read (rows wv*8..wv*8+7 only): in-order, no barrier
        hrow[nl * 17 + hh8 * 2]     = lo;
        hrow[nl * 17 + hh8 * 2 + 1] = hi;
        const int hh = lane;
        const int nb = blockIdx.x * 32 + wv * 8;
        float acc[8];
#pragma unroll
        for (int s8 = 0; s8 < 8; ++s8) acc[s8] = 0.f;
#pragma unroll 2
        for (int k4 = 0; k4 < 16; ++k4) {
            float4 w = Wt[k4 * 65 + hh];
#pragma unroll
            for (int s8 = 0; s8 < 8; ++s8) {
                float4 hv = hrow[(wv * 8 + s8) * 17 + k4];   // wave-broadcast (free)
                acc[s8] += hv.x * w.x + hv.y * w.y + hv.z * w.z + hv.w * w.w;
            }
        }
#pragma unroll
        for (int s8 = 0; s8 < 8; ++s8) {
            int ns = nb + s8;
            if (ns < N_NODES) {
                float dd = rsqrtf((float)fill[ns] + 1.0f);
                gout[(size_t)ns * HID + hh] = __float2half(acc[s8] * dd);
            }
        }
    }
}

// ---------------- pool + final linear: one 1024-thread block per graph ----------------
__device__ __forceinline__ int lowerb(const int* __restrict__ b, int val) {
    int lo = 0, hi = N_NODES;
    while (lo < hi) {
        int mid = (lo + hi) >> 1;
        if (b[mid] < val) lo = mid + 1; else hi = mid;
    }
    return lo;
}

__global__ __launch_bounds__(1024) void k_poolfinal(const float* __restrict__ h,
                                                    const int* __restrict__ batch,
                                                    const float* __restrict__ lin_w,
                                                    const float* __restrict__ lin_b,
                                                    float* __restrict__ out) {
    __shared__ float red[16][HID];
    int g = blockIdx.x;
    int w = threadIdx.x >> 6;
    int hh = threadIdx.x & 63;
    int start = lowerb(batch, g);
    int end = lowerb(batch, g + 1);
    int len = end - start;
    float acc = 0.f;
    for (int n = start + w; n < end; n += 16) acc += h[n * HID + hh];
    red[w][hh] = acc;
    __syncthreads();
    if (w == 0) {
        float s = 0.f;
#pragma unroll
        for (int i = 0; i < 16; ++i) s += red[i][hh];
        float c = fmaxf((float)len, 1.0f);
        float v = (s / c) * lin_w[hh];
#pragma unroll
        for (int off = 32; off > 0; off >>= 1) v += __shfl_down(v, off);
        if (hh == 0) out[g] = v + lin_b[0];
    }
}

extern "C" void kernel_launch(void* const* d_in, const int* in_sizes, int n_in,
                              void* d_out, int out_size, void* d_ws, size_t ws_size,
                              hipStream_t stream) {
    const float* x     = (const float*)d_in[0];
    const int*   ei    = (const int*)d_in[1];
    const int*   batch = (const int*)d_in[2];
    const float* W_in  = (const float*)d_in[3];
    const float* W1    = (const float*)d_in[4];
    const float* b1    = (const float*)d_in[5];
    const float* Ws    = (const float*)d_in[6];
    const float* bs_   = (const float*)d_in[7];
    const float* bn_g  = (const float*)d_in[8];
    const float* bn_b  = (const float*)d_in[9];
    const float* bn_m  = (const float*)d_in[10];
    const float* bn_v  = (const float*)d_in[11];
    const float* lin_w = (const float*)d_in[12];
    const float* lin_b = (const float*)d_in[13];
    float* out = (float*)d_out;

    char* q = (char*)d_ws;
    int*            fill = (int*)q;             q += (size_t)50048 * 4;
    unsigned short* colp = (unsigned short*)q;  q += (size_t)N_NODES * MAXDEG * 2;
    __half*         g16a = (__half*)q;          q += (size_t)N_NODES * HID * 2;
    __half*         g16b = (__half*)q;          q += (size_t)N_NODES * HID * 2;
    float*          h    = (float*)q;           q += (size_t)N_NODES * HID * 4;

    const int NB_N  = NB256(N_NODES);
    const int NB_GA = (N_NODES + 31) / 32;   // 1563
    float4* h4 = (float4*)h;

    // zero fill, then fused dual-GEMM (identity + layer-1) with deferred-store edge placement
    k_zero<<<NB_N, 256, 0, stream>>>(fill);
    k_gemmedge<<<GE_NB, 256, 0, stream>>>(ei, fill, colp, x, W_in, W1, h, g16a);

    // layer 1: gather (per-source dinv; g16a unscaled) + fused gemm for layer 2
    k_gather_fused<true, true><<<NB_GA, 256, 0, stream>>>(
        g16a, colp, fill, b1, bn_g, bn_b, bn_m, bn_v,
        (const float4*)h, h4, Ws + 0 * HID * HID, g16b);

    // layers 2-4: gather (pre-scaled g16) + fused gemm for next layer
    k_gather_fused<false, true><<<NB_GA, 256, 0, stream>>>(
        g16b, colp, fill, bs_ + 0 * HID,
        bn_g + 1 * HID, bn_b + 1 * HID, bn_m + 1 * HID, bn_v + 1 * HID,
        (const float4*)h, h4, Ws + 1 * HID * HID, g16a);

    k_gather_fused<false, true><<<NB_GA, 256, 0, stream>>>(
        g16a, colp, fill, bs_ + 1 * HID,
        bn_g + 2 * HID, bn_b + 2 * HID, bn_m + 2 * HID, bn_v + 2 * HID,
        (const float4*)h, h4, Ws + 2 * HID * HID, g16b);

    k_gather_fused<false, true><<<NB_GA, 256, 0, stream>>>(
        g16b, colp, fill, bs_ + 2 * HID,
        bn_g + 3 * HID, bn_b + 3 * HID, bn_m + 3 * HID, bn_v + 3 * HID,
        (const float4*)h, h4, Ws + 3 * HID * HID, g16a);

    // layer 5: gather only (no residual, no next gemm)
    k_gather_fused<false, false><<<NB_GA, 256, 0, stream>>>(
        g16a, colp, fill, bs_ + 3 * HID,
        bn_g + 4 * HID, bn_b + 4 * HID, bn_m + 4 * HID, bn_v + 4 * HID,
        nullptr, h4, nullptr, nullptr);

    // pool + final
    k_poolfinal<<<N_GRAPHS, 1024, 0, stream>>>(h, batch, lin_w, lin_b, out);
}